// Round 8
// baseline (121.782 us; speedup 1.0000x reference)
//
#include <hip/hip_runtime.h>
#include <hip/hip_bf16.h>

// MultiHeadAttention fused pipeline, round 8: counted-vmcnt attention pipeline.
// B=2 S=2048 D=1024 H=16 dk=64.
// ws layout (48 MB): Xb 8M | Wq/Wk/Wv/Wo bf16 2M each | Qb 8M | Kb 8M | Vt 8M | Ob 8M
// Changes vs R7 (attn only; R5/R6/R7 all pinned at ~48us by 32 draining
// __syncthreads phases -> test the phase-drain theory):
//  - raw s_barrier + inline-asm counted s_waitcnt vmcnt(4): next-tile
//    global_load_lds stays in flight across barriers (T4); never drain to 0
//    in the main loop.
//  - 16 phases of 128 staged keys (64/half, 2 procs per wave per phase),
//    double-buffered 64KB LDS; merge buffer aliased onto dead K/V LDS.

typedef unsigned short u16;
typedef __attribute__((ext_vector_type(4))) unsigned short u16x4;
typedef __attribute__((ext_vector_type(8))) short short8;   // 8 x bf16 (4 VGPRs)
typedef __attribute__((ext_vector_type(4))) float f32x4;

__device__ __forceinline__ u16 f2bf(float f) {  // native RNE f32->bf16
  __bf16 b = (__bf16)f;
  return __builtin_bit_cast(unsigned short, b);
}

__device__ __forceinline__ f32x4 mfma_bf16(short8 a, short8 b, f32x4 c) {
  return __builtin_amdgcn_mfma_f32_16x16x32_bf16(a, b, c, 0, 0, 0);
}

#define GLL16(gp, lp) __builtin_amdgcn_global_load_lds( \
    (const __attribute__((address_space(1))) void*)(gp), \
    (__attribute__((address_space(3))) void*)(lp), 16, 0, 0)

#define WAITV4 asm volatile("s_waitcnt vmcnt(4)" ::: "memory")
#define WAITV0 asm volatile("s_waitcnt vmcnt(0)" ::: "memory")
#define BAR __builtin_amdgcn_s_barrier()

#define QSCALE 0.18033688011112042f   /* 0.125 * log2(e) */

// ---------------------------------------------------------------- casts
__global__ __launch_bounds__(256) void cast_all(
    const float* __restrict__ x,
    const float* __restrict__ wq, const float* __restrict__ wk,
    const float* __restrict__ wv, const float* __restrict__ wo,
    u16* __restrict__ xb, u16* __restrict__ wqb, u16* __restrict__ wkb,
    u16* __restrict__ wvb, u16* __restrict__ wob)
{
  const int z = blockIdx.z;
  const float* s; u16* d; int n4;
  if (z == 0)      { s = x;  d = xb;  n4 = 1048576; }
  else if (z == 1) { s = wq; d = wqb; n4 = 262144; }
  else if (z == 2) { s = wk; d = wkb; n4 = 262144; }
  else if (z == 3) { s = wv; d = wvb; n4 = 262144; }
  else             { s = wo; d = wob; n4 = 262144; }
  int i = blockIdx.x * 256 + threadIdx.x;
  if (i >= n4) return;
  float4 v = ((const float4*)s)[i];
  u16x4 o; o[0] = f2bf(v.x); o[1] = f2bf(v.y); o[2] = f2bf(v.z); o[3] = f2bf(v.w);
  ((u16x4*)d)[i] = o;
}

// -------------------------------------------------- 128x128 GEMM core, C = A * B^T
__device__ __forceinline__ void gemm_core(const u16* __restrict__ A,
                                          const u16* __restrict__ B,
                                          u16* sA, u16* sB, f32x4 acc[4][4])
{
  const int tid = threadIdx.x;
  const int lane = tid & 63, wave = tid >> 6;
  const int wr = wave >> 1, wc = wave & 1;
  const int m0 = blockIdx.y * 128, n0 = blockIdx.x * 128;
  const u16* ga = A + (size_t)(m0 + (tid >> 2)) * 1024 + (tid & 3) * 8;
  const u16* gb = B + (size_t)(n0 + (tid >> 2)) * 1024 + (tid & 3) * 8;
  u16* la0 = sA + wave * 512;          u16* la1 = sA + 2048 + wave * 512;
  u16* lb0 = sB + wave * 512;          u16* lb1 = sB + 2048 + wave * 512;
  const int rl = lane & 15, kg = (lane >> 4) * 8;

  for (int k0 = 0; k0 < 1024; k0 += 32) {
    GLL16(ga + k0,             la0);
    GLL16(ga + 64 * 1024 + k0, la1);
    GLL16(gb + k0,             lb0);
    GLL16(gb + 64 * 1024 + k0, lb1);
    __syncthreads();
    short8 af[4], bf_[4];
#pragma unroll
    for (int m = 0; m < 4; ++m) af[m]  = *(const short8*)&sA[(wr * 64 + m * 16 + rl) * 32 + kg];
#pragma unroll
    for (int n = 0; n < 4; ++n) bf_[n] = *(const short8*)&sB[(wc * 64 + n * 16 + rl) * 32 + kg];
#pragma unroll
    for (int m = 0; m < 4; ++m)
#pragma unroll
      for (int n = 0; n < 4; ++n)
        acc[m][n] = mfma_bf16(af[m], bf_[n], acc[m][n]);
    __syncthreads();
  }
}

// QKV projections fused via blockIdx.z. z=0 -> Q (PRE-SCALED by QSCALE),
// z=1 -> K, z=2 -> V written TRANSPOSED: Vt[(b*1024+hd)][s].
__global__ __launch_bounds__(256) void gemm_qkv(
    const u16* __restrict__ X,
    const u16* __restrict__ Wqb, const u16* __restrict__ Wkb, const u16* __restrict__ Wvb,
    const float* __restrict__ bq, const float* __restrict__ bk, const float* __restrict__ bv,
    u16* __restrict__ Qo, u16* __restrict__ Ko, u16* __restrict__ Vt)
{
  __shared__ u16 sA[4096], sB[4096];
  const int z = blockIdx.z;
  const u16* W = (z == 0) ? Wqb : (z == 1) ? Wkb : Wvb;
  const float* bias = (z == 0) ? bq : (z == 1) ? bk : bv;

  f32x4 acc[4][4];
#pragma unroll
  for (int m = 0; m < 4; ++m)
#pragma unroll
    for (int n = 0; n < 4; ++n) acc[m][n] = (f32x4){0.f, 0.f, 0.f, 0.f};

  gemm_core(X, W, sA, sB, acc);

  const int lane = threadIdx.x & 63, wave = threadIdx.x >> 6;
  const int wr = wave >> 1, wc = wave & 1;
  const int m0 = blockIdx.y * 128, n0 = blockIdx.x * 128;
  const int rl = lane & 15, rg = (lane >> 4) * 4;

  if (z < 2) {
    u16* dst = (z == 0) ? Qo : Ko;
    const float cs = (z == 0) ? QSCALE : 1.0f;
#pragma unroll
    for (int n = 0; n < 4; ++n) {
      int col = n0 + wc * 64 + n * 16 + rl;
      float bb = bias[col];
#pragma unroll
      for (int m = 0; m < 4; ++m) {
        int row0 = m0 + wr * 64 + m * 16 + rg;
#pragma unroll
        for (int r = 0; r < 4; ++r)
          dst[(size_t)(row0 + r) * 1024 + col] = f2bf((acc[m][n][r] + bb) * cs);
      }
    }
  } else {
#pragma unroll
    for (int n = 0; n < 4; ++n) {
      int col = n0 + wc * 64 + n * 16 + rl;   // hd = h*64+d
      float bb = bias[col];
#pragma unroll
      for (int m = 0; m < 4; ++m) {
        int row0 = m0 + wr * 64 + m * 16 + rg;          // b*2048 + s
        int bidx = row0 >> 11, sl = row0 & 2047;
        u16x4 pk;
#pragma unroll
        for (int r = 0; r < 4; ++r) pk[r] = f2bf(acc[m][n][r] + bb);
        *(u16x4*)&Vt[((size_t)(bidx * 1024 + col)) * 2048 + sl] = pk;
      }
    }
  }
}

// Output projection: out(fp32) = Ob @ Wo^T + bo
__global__ __launch_bounds__(256) void gemm_out(
    const u16* __restrict__ Ob, const u16* __restrict__ Wob,
    const float* __restrict__ bo, float* __restrict__ Out)
{
  __shared__ u16 sA[4096], sB[4096];
  f32x4 acc[4][4];
#pragma unroll
  for (int m = 0; m < 4; ++m)
#pragma unroll
    for (int n = 0; n < 4; ++n) acc[m][n] = (f32x4){0.f, 0.f, 0.f, 0.f};

  gemm_core(Ob, Wob, sA, sB, acc);

  const int lane = threadIdx.x & 63, wave = threadIdx.x >> 6;
  const int wr = wave >> 1, wc = wave & 1;
  const int m0 = blockIdx.y * 128, n0 = blockIdx.x * 128;
  const int rl = lane & 15, rg = (lane >> 4) * 4;
#pragma unroll
  for (int n = 0; n < 4; ++n) {
    int col = n0 + wc * 64 + n * 16 + rl;
    float bb = bo[col];
#pragma unroll
    for (int m = 0; m < 4; ++m) {
      int row0 = m0 + wr * 64 + m * 16 + rg;
#pragma unroll
      for (int r = 0; r < 4; ++r)
        Out[(size_t)(row0 + r) * 1024 + col] = acc[m][n][r] + bb;
    }
  }
}

// ---------------------------------------------------------------- flash attention
// Split-KV: block = 512 thr = 8 waves = 4 q-slots (32 q) x 2 K-halves.
// 16 phases; each stages 64 keys per half (K 16KB + V 16KB) into the other
// LDS buffer while both procs of the current buffer run. Counted vmcnt(4)
// keeps the newest stage in flight across barriers (no drain).
// smem carve: sK 2x[128][64] (32KB) | sV 2x[64][128] (32KB); merge buffer
// aliases the front 36KB after the K-loop (K/V dead by then).
__global__ __launch_bounds__(512) void attn_fwd(
    const u16* __restrict__ Q, const u16* __restrict__ K,
    const u16* __restrict__ Vt, u16* __restrict__ O)
{
  __shared__ u16 smem[32768];   // 64KB
#define SKa(nb, r) (&smem[(nb) * 8192 + (r) * 64])
#define SVa(nb, r) (&smem[16384 + (nb) * 8192 + (r) * 128])

  const int tid = threadIdx.x, lane = tid & 63, wave = tid >> 6;  // wave 0..7
  const int rl = lane & 15, g = lane >> 4;
  const int qslot = wave >> 1, half = wave & 1;

  const int bflat = blockIdx.x;
  const int xcd = bflat & 7, j = bflat >> 3;        // 512 = 8 XCD * 64
  const int bh = xcd * 4 + (j >> 4);                // 4 bh per XCD (2MB in L2)
  const int qidx = j & 15;
  const int b = bh >> 4, h = bh & 15;
  const int qbase = qidx * 128 + qslot * 32;

  const u16* Qp = Q + (size_t)(b * 2048 + qbase) * 1024 + h * 64;
  const u16* Kp = K + (size_t)(b * 2048) * 1024 + h * 64;
  const u16* Vp = Vt + (size_t)(bh * 64) * 2048;

  short8 qf[2][2];
#pragma unroll
  for (int qg = 0; qg < 2; ++qg)
#pragma unroll
    for (int hf = 0; hf < 2; ++hf)
      qf[qg][hf] = *(const short8*)&Qp[(size_t)(qg * 16 + rl) * 1024 + hf * 32 + g * 8];

  const int keyperm = 8 * (rl >> 2) + (rl & 3);
  const int swzK8 = (((rl & 3) | (((rl >> 2) & 1) << 2))) * 8;

  // --- staging constants (thread-fixed). K: GLL i covers sK rows widx_i*8..+8,
  // widx = wave*2+i; global row = (widx>>3)*1024 + t*64 + (widx&7)*8 + (lane>>3);
  // inverse-swizzle source slot = (lane&7) ^ ((lane>>3)&3) ^ (i<<2).
  const int widx0 = wave * 2, widx1 = wave * 2 + 1;
  const int krow0 = ((widx0 >> 3) << 10) + ((widx0 & 7) << 3) + (lane >> 3);
  const int krow1 = ((widx1 >> 3) << 10) + ((widx1 & 7) << 3) + (lane >> 3);
  const int kslot0 = (((lane & 7) ^ ((lane >> 3) & 3)) << 3);
  const int kslot1 = ((((lane & 7) ^ ((lane >> 3) & 3)) ^ 4) << 3);
  // V: GLL i covers sV rows widx_i*4..+4; d = widx_i*4 + (lane>>4);
  // source group = halfV*1024-range, lg = (lane&7) ^ (i*4 + (lane>>4)).
  const int vd0 = widx0 * 4 + (lane >> 4), vd1 = widx1 * 4 + (lane >> 4);
  const int vhalfoff = ((lane >> 3) & 1) << 10;
  const int vlg0 = ((lane & 7) ^ (lane >> 4)) << 3;
  const int vlg1 = ((lane & 7) ^ (4 + (lane >> 4))) << 3;

  f32x4 oacc[2][4];
  f32x4 lacc[2];
#pragma unroll
  for (int qg = 0; qg < 2; ++qg) {
    lacc[qg] = (f32x4){0.f, 0.f, 0.f, 0.f};
#pragma unroll
    for (int dg = 0; dg < 4; ++dg) oacc[qg][dg] = (f32x4){0.f, 0.f, 0.f, 0.f};
  }
  float mrun[2] = {-INFINITY, -INFINITY};

  const short8 ONES = {0x3F80, 0x3F80, 0x3F80, 0x3F80,
                       0x3F80, 0x3F80, 0x3F80, 0x3F80};  // bf16 1.0 x8

  // stage tile t (64 keys per half): 2 K-GLL + 2 V-GLL per thread
  auto stage = [&](int nb, int t) {
    GLL16(Kp + (size_t)(krow0 + t * 64) * 1024 + kslot0, SKa(nb, widx0 * 8));
    GLL16(Kp + (size_t)(krow1 + t * 64) * 1024 + kslot1, SKa(nb, widx1 * 8));
    GLL16(Vp + (size_t)vd0 * 2048 + vhalfoff + t * 64 + vlg0, SVa(nb, widx0 * 4));
    GLL16(Vp + (size_t)vd1 * 2048 + vhalfoff + t * 64 + vlg1, SVa(nb, widx1 * 4));
  };

  // process 32-key subtile `sub` (0/1) of this wave's half from buffer nb
  auto proc = [&](int nb, int sub) {
    short8 kf[2][2];
#pragma unroll
    for (int t2 = 0; t2 < 2; ++t2) {
      const int r = half * 64 + sub * 32 + keyperm + 4 * t2;
#pragma unroll
      for (int hf = 0; hf < 2; ++hf)
        kf[t2][hf] = *(const short8*)&SKa(nb, r)[(hf * 32 + g * 8) ^ swzK8];
    }
    short8 vf[4];
#pragma unroll
    for (int dg = 0; dg < 4; ++dg)
      vf[dg] = *(const short8*)&SVa(nb, dg * 16 + rl)
                   [(((half << 3) | ((sub * 4 + g) ^ (rl & 7)))) * 8];

    f32x4 sc[2][2];
    __builtin_amdgcn_s_setprio(1);
#pragma unroll
    for (int qg = 0; qg < 2; ++qg)
#pragma unroll
      for (int t2 = 0; t2 < 2; ++t2) {
        f32x4 a = (f32x4){0.f, 0.f, 0.f, 0.f};
        a = mfma_bf16(kf[t2][0], qf[qg][0], a);
        a = mfma_bf16(kf[t2][1], qf[qg][1], a);
        sc[qg][t2] = a;
      }
    __builtin_amdgcn_s_setprio(0);

    short8 pb[2];
#pragma unroll
    for (int qg = 0; qg < 2; ++qg) {
      float p2[8];
#pragma unroll
      for (int t2 = 0; t2 < 2; ++t2)
#pragma unroll
        for (int r = 0; r < 4; ++r) p2[t2 * 4 + r] = sc[qg][t2][r];
      float a0 = fmaxf(fmaxf(p2[0], p2[1]), p2[2]);
      float a1 = fmaxf(fmaxf(p2[3], p2[4]), p2[5]);
      float a2 = fmaxf(p2[6], p2[7]);
      float tm = fmaxf(fmaxf(a0, a1), a2);
      // defer-max: rescale only when tile max grows past THR=8 (exp2 domain)
      if (!__all(tm <= mrun[qg] + 8.0f)) {
        tm = fmaxf(tm, __shfl_xor(tm, 16));
        tm = fmaxf(tm, __shfl_xor(tm, 32));
        float mnew = fmaxf(mrun[qg], tm);
        float sfac = __builtin_amdgcn_exp2f(mrun[qg] - mnew);
        mrun[qg] = mnew;
#pragma unroll
        for (int dg = 0; dg < 4; ++dg)
#pragma unroll
          for (int r = 0; r < 4; ++r) oacc[qg][dg][r] *= sfac;
        lacc[qg][0] *= sfac;   // only reg 0 is ever read
      }
      short8 pk;
#pragma unroll
      for (int j2 = 0; j2 < 8; ++j2)
        pk[j2] = (short)f2bf(__builtin_amdgcn_exp2f(p2[j2] - mrun[qg]));
      pb[qg] = pk;
      lacc[qg] = mfma_bf16(ONES, pb[qg], lacc[qg]);   // row-sum on matrix pipe
    }
    __builtin_amdgcn_s_setprio(1);
#pragma unroll
    for (int dg = 0; dg < 4; ++dg)
#pragma unroll
      for (int qg = 0; qg < 2; ++qg)
        oacc[qg][dg] = mfma_bf16(vf[dg], pb[qg], oacc[qg][dg]);
    __builtin_amdgcn_s_setprio(0);
  };

  // ---- pipelined main loop: 16 tiles of 64 keys/half, counted vmcnt ----
  stage(0, 0);
  stage(1, 1);
  for (int t = 0; t < 14; ++t) {
    WAITV4; BAR;               // tile t's 4 GLLs done; t+1's stay in flight
    proc(t & 1, 0);
    proc(t & 1, 1);
    BAR;                       // all waves done reading buf[t&1]
    stage(t & 1, t + 2);       // overwrite it with tile t+2
  }
  WAITV4; BAR;
  proc(0, 0); proc(0, 1);      // tile 14
  WAITV0; BAR;
  proc(1, 0); proc(1, 1);      // tile 15
  __syncthreads();             // K/V LDS dead; reuse as merge buffer

  // merge the two K-halves (online-softmax combine), half1 -> mbuf -> half0
  float* mbuf = (float*)smem;  // 4 qslots x 64 lanes x 36 floats = 36KB
  const int mb = (qslot * 64 + lane) * 36;
  if (half == 1) {
#pragma unroll
    for (int qg = 0; qg < 2; ++qg) {
#pragma unroll
      for (int dg = 0; dg < 4; ++dg)
#pragma unroll
        for (int r = 0; r < 4; ++r)
          mbuf[mb + qg * 18 + dg * 4 + r] = oacc[qg][dg][r];
      mbuf[mb + qg * 18 + 16] = mrun[qg];
      mbuf[mb + qg * 18 + 17] = lacc[qg][0];
    }
  }
  __syncthreads();
  if (half == 0) {
#pragma unroll
    for (int qg = 0; qg < 2; ++qg) {
      float m2 = mbuf[mb + qg * 18 + 16];
      float l2 = mbuf[mb + qg * 18 + 17];
      float mnew = fmaxf(mrun[qg], m2);
      float fa = __builtin_amdgcn_exp2f(mrun[qg] - mnew);
      float fb = __builtin_amdgcn_exp2f(m2 - mnew);
      float inv = 1.0f / (lacc[qg][0] * fa + l2 * fb);
      int qrow = qbase + qg * 16 + rl;
      u16* op = O + (size_t)(b * 2048 + qrow) * 1024 + h * 64;
#pragma unroll
      for (int dg = 0; dg < 4; ++dg) {
        u16x4 pk;
#pragma unroll
        for (int r = 0; r < 4; ++r)
          pk[r] = f2bf((oacc[qg][dg][r] * fa + mbuf[mb + qg * 18 + dg * 4 + r] * fb) * inv);
        *(u16x4*)&op[dg * 16 + g * 4] = pk;
      }
    }
  }
#undef SKa
#undef SVa
}

// ---------------------------------------------------------------- launch
extern "C" void kernel_launch(void* const* d_in, const int* in_sizes, int n_in,
                              void* d_out, int out_size, void* d_ws, size_t ws_size,
                              hipStream_t stream) {
  const float* x  = (const float*)d_in[0];
  const float* Wq = (const float*)d_in[1];
  const float* bq = (const float*)d_in[2];
  const float* Wk = (const float*)d_in[3];
  const float* bk = (const float*)d_in[4];
  const float* Wv = (const float*)d_in[5];
  const float* bv = (const float*)d_in[6];
  const float* Wo = (const float*)d_in[7];
  const float* bo = (const float*)d_in[8];

  char* ws = (char*)d_ws;
  const size_t MB = 1024 * 1024;
  u16* Xb  = (u16*)(ws + 0 * MB);
  u16* Wqb = (u16*)(ws + 8 * MB);
  u16* Wkb = (u16*)(ws + 10 * MB);
  u16* Wvb = (u16*)(ws + 12 * MB);
  u16* Wob = (u16*)(ws + 14 * MB);
  u16* Qb  = (u16*)(ws + 16 * MB);
  u16* Kb  = (u16*)(ws + 24 * MB);
  u16* Vtb = (u16*)(ws + 32 * MB);
  u16* Ob  = (u16*)(ws + 40 * MB);

  cast_all<<<dim3(4096, 1, 5), 256, 0, stream>>>(x, Wq, Wk, Wv, Wo,
                                                 Xb, Wqb, Wkb, Wvb, Wob);
  gemm_qkv<<<dim3(8, 32, 3), 256, 0, stream>>>(Xb, Wqb, Wkb, Wvb,
                                               bq, bk, bv, Qb, Kb, Vtb);
  attn_fwd<<<dim3(512), 512, 0, stream>>>(Qb, Kb, Vtb, Ob);
  gemm_out<<<dim3(8, 32), 256, 0, stream>>>(Ob, Wob, bo, (float*)d_out);
}